// Round 10
// baseline (60.549 us; speedup 1.0000x reference)
//
#include <hip/hip_runtime.h>
#include <math.h>

#define BS 8
#define P 8192
#define G 16
#define DIM 512

#define BLOCK 256
#define WAVES 4
#define RPG 2                                   // rows per 8-lane group
#define ROWS_PER_WAVE 16                        // 8 groups x RPG
#define ROWS_PER_BLOCK (WAVES * ROWS_PER_WAVE)  // 64 -> grid 1024 = 4 blocks/CU
#define BLOCKS_PER_BATCH (P / ROWS_PER_BLOCK)   // 128
#define KC 32                                   // cols per k-chunk
#define NKC (DIM / KC)                          // 16 chunks
#define CHUNK_FLOATS (ROWS_PER_WAVE * KC)       // 512 floats = 2 KB

__device__ __forceinline__ float smooth_l1(float d) {
    float a = fabsf(d);
    return a < 1.0f ? 0.5f * d * d : a - 0.5f;
}

__device__ __forceinline__ float dot4(float4 a, float4 b) {
    return a.x * b.x + a.y * b.y + a.z * b.z + a.w * b.w;
}

// Fire-and-forget global->LDS DMA, 16B/lane; LDS dest = uniform base + lane*16.
__device__ __forceinline__ void load16_to_lds(const float* gsrc, float* ldst) {
    __builtin_amdgcn_global_load_lds(
        (const __attribute__((address_space(1))) void*)gsrc,
        (__attribute__((address_space(3))) void*)ldst,
        16, 0, 0);
}

// Stage one 16-row x 32-col chunk (2 KB) of this wave's rows: 2 issues.
// Issue j covers rows j*8..j*8+7; lane's 16B lands at LDS float offset
// j*256 + lane*4 == (row-in-chunk)*32 + (lane&7)*4  -> linear [16][32].
__device__ __forceinline__ void stage_chunk(const float* __restrict__ vwave,
                                            int kc, float* dst, int lane) {
    const float* src0 = vwave + (size_t)kc * KC + (size_t)(lane >> 3) * DIM + (lane & 7) * 4;
    #pragma unroll
    for (int j = 0; j < 2; ++j)
        load16_to_lds(src0 + (size_t)j * 8 * DIM, dst + j * 256);
}

// launch_bounds (256,1): no VGPR clamp (",4"/",2" caused 10-421 MB scratch
// spills in r2-r4). Occupancy: LDS ~34 KB + VGPR ~64 -> 4 blocks/CU = 16 waves.
__global__ __launch_bounds__(BLOCK, 1)
void det_main(const float* __restrict__ v,
              const float* __restrict__ gt,
              const float* __restrict__ rois,
              const float* __restrict__ labels,
              const float* __restrict__ pre_score,
              const float* __restrict__ cls_w,
              const float* __restrict__ cls_b,
              const float* __restrict__ reg_w,
              const float* __restrict__ reg_b,
              float* __restrict__ partials)   // [BS][3]: cnum, cden, l1
{
    const int tid  = threadIdx.x;
    const int lane = tid & 63;
    const int w    = tid >> 6;      // wave 0..3
    const int grp  = lane >> 3;     // 8-lane group 0..7
    const int l    = lane & 7;      // lane within group
    const int b    = blockIdx.x / BLOCKS_PER_BATCH;
    const int blk  = blockIdx.x % BLOCKS_PER_BATCH;
    const int p0   = blk * ROWS_PER_BLOCK;
    const int wrow0 = p0 + w * ROWS_PER_WAVE;   // this wave's first row

    __shared__ float s_w[8 * DIM];                       // 16 KB weights
    __shared__ float s_v[WAVES][2][CHUNK_FLOATS];        // 16 KB, 2-buf/wave
    __shared__ float s_rois[ROWS_PER_BLOCK * 4];         // 1 KB
    __shared__ float s_ps[ROWS_PER_BLOCK];               // 256 B
    __shared__ float s_gt[G * 4];
    __shared__ float s_red[WAVES][3];

    const float* vwave = v + ((size_t)b * P + wrow0) * DIM;

    // ---- label argmax: uniform, computed redundantly by every thread
    const float* lb = labels + b * 4;
    int lab = 0; float lm = lb[0];
    { float t = lb[1]; if (t > lm) { lm = t; lab = 1; } }
    { float t = lb[2]; if (t > lm) { lm = t; lab = 2; } }
    { float t = lb[3]; if (t > lm) { lm = t; lab = 3; } }

    // ---- issue DMA for chunk 0 first (latency hides under staging below)
    stage_chunk(vwave, 0, &s_v[w][0][0], lane);

    // ---- stage weights (16 KB), rois (1 KB), ps, gt
    {
        const float4* cw = (const float4*)cls_w;   // 512 float4
        const float4* rw = (const float4*)reg_w;   // 512 float4
        float4* sw = (float4*)s_w;
        sw[tid]       = cw[tid];
        sw[256 + tid] = cw[256 + tid];
        sw[512 + tid] = rw[tid];
        sw[768 + tid] = rw[256 + tid];
    }
    if (tid < ROWS_PER_BLOCK) {
        ((float4*)s_rois)[tid] = ((const float4*)rois)[(size_t)b * P + p0 + tid];
        s_ps[tid] = pre_score[((size_t)b * P + p0 + tid) * 4 + lab];
    }
    if (tid < G * 4) s_gt[tid] = gt[b * G * 4 + tid];
    __syncthreads();   // drains prologue (incl. chunk-0 DMA) -> vmcnt = 0

    const float cb0 = cls_b[0], cb1 = cls_b[1], cb2 = cls_b[2], cb3 = cls_b[3];
    const float rb0 = reg_b[0], rb1 = reg_b[1], rb2 = reg_b[2], rb3 = reg_b[3];

    // ---- main loop: 16 k-chunks, double-buffered, counted vmcnt (never 0
    // until the last chunk). No block barriers: chunks are wave-private.
    // Double-buffer WAR safety: this wave's ds_reads of buf[x] complete
    // (lgkmcnt drained before their FMA uses) BEFORE it issues the next DMA
    // into buf[x] in program order.
    float acc[8][RPG];
    #pragma unroll
    for (int c = 0; c < 8; ++c)
        #pragma unroll
        for (int r = 0; r < RPG; ++r) acc[c][r] = 0.0f;

    #pragma unroll 2
    for (int kc = 0; kc < NKC; ++kc) {
        const int cur = kc & 1;
        // prefetch next chunk, then wait only for the current one
        if (kc + 1 < NKC) {
            stage_chunk(vwave, kc + 1, &s_v[w][cur ^ 1][0], lane);
            asm volatile("s_waitcnt vmcnt(2)" ::: "memory");
        } else {
            asm volatile("s_waitcnt vmcnt(0)" ::: "memory");
        }

        const float* vb = &s_v[w][cur][(grp * RPG) * KC + l * 4];
        float4 x0 = *(const float4*)(vb + 0 * KC);
        float4 x1 = *(const float4*)(vb + 1 * KC);
        // weight reads broadcast across the 8 groups (addr depends on l only)
        #pragma unroll
        for (int c = 0; c < 8; ++c) {
            float4 wv = *(const float4*)&s_w[c * DIM + kc * KC + l * 4];
            acc[c][0] += dot4(wv, x0);
            acc[c][1] += dot4(wv, x1);
        }
    }

    // ---- reduce across the 8 lanes of each group (3 butterfly steps)
    #pragma unroll
    for (int c = 0; c < 8; ++c)
        #pragma unroll
        for (int r = 0; r < RPG; ++r) {
            float x = acc[c][r];
            x += __shfl_xor(x, 1);
            x += __shfl_xor(x, 2);
            x += __shfl_xor(x, 4);
            acc[c][r] = x;
        }

    // ---- epilogue: lane l (<RPG) of each group handles its group's row l
    float acc_cnum = 0.0f, acc_cden = 0.0f, acc_l1 = 0.0f;
    if (l < RPG) {
        float d[8];
        #pragma unroll
        for (int r = 0; r < RPG; ++r)
            if (l == r) {
                #pragma unroll
                for (int c = 0; c < 8; ++c) d[c] = acc[c][r];
            }
        const int lrow = w * ROWS_PER_WAVE + grp * RPG + l;  // block-local row
        const float4 rbox = *(const float4*)&s_rois[lrow * 4];
        const float ps = s_ps[lrow];
        const float area_r = (rbox.z - rbox.x) * (rbox.w - rbox.y);

        float biou = -1.0f; int bidx = 0;
        #pragma unroll
        for (int gi = 0; gi < G; ++gi) {
            float g0 = s_gt[gi * 4 + 0], g1 = s_gt[gi * 4 + 1];
            float g2 = s_gt[gi * 4 + 2], g3 = s_gt[gi * 4 + 3];
            float ltx = fmaxf(g0, rbox.x), lty = fmaxf(g1, rbox.y);
            float rbx = fminf(g2, rbox.z), rby = fminf(g3, rbox.w);
            float wx = fmaxf(rbx - ltx, 0.0f), wy = fmaxf(rby - lty, 0.0f);
            float inter = wx * wy;
            float ag = (g2 - g0) * (g3 - g1);
            float iou = inter / (ag + area_r - inter);
            if (iou > biou) { biou = iou; bidx = gi; }
        }
        const float mask = biou > 0.5f ? 1.0f : 0.0f;

        // cross-entropy on clipped logits
        float c0 = fminf(fmaxf(d[0] + cb0, 1e-7f), 0.99999994f);
        float c1 = fminf(fmaxf(d[1] + cb1, 1e-7f), 0.99999994f);
        float c2 = fminf(fmaxf(d[2] + cb2, 1e-7f), 0.99999994f);
        float c3 = fminf(fmaxf(d[3] + cb3, 1e-7f), 0.99999994f);
        float m  = fmaxf(fmaxf(c0, c1), fmaxf(c2, c3));
        float s  = expf(c0 - m) + expf(c1 - m) + expf(c2 - m) + expf(c3 - m);
        float lse = m + logf(s);
        float csel = lab == 0 ? c0 : (lab == 1 ? c1 : (lab == 2 ? c2 : c3));
        float ce = lse - csel;

        acc_cnum = ce * ps * mask;
        acc_cden = mask;

        // regression loss vs best-GT targets
        float bg0 = s_gt[bidx * 4 + 0], bg1 = s_gt[bidx * 4 + 1];
        float bg2 = s_gt[bidx * 4 + 2], bg3 = s_gt[bidx * 4 + 3];
        float gx = (bg2 + bg0) * 0.5f, gy = (bg3 + bg1) * 0.5f;
        float gw = (bg2 - bg0) * 0.5f, gh = (bg3 - bg1) * 0.5f;
        float rx = (rbox.z + rbox.x) * 0.5f, ry = (rbox.w + rbox.y) * 0.5f;
        float rw_ = (rbox.z - rbox.x) * 0.5f, rh = (rbox.w - rbox.y) * 0.5f;
        float tx = (gx - rx) / (rw_ + 1e-8f);
        float ty = (gy - ry) / (rh + 1e-8f);
        float tw = logf(gw / (rw_ + 1e-8f));
        float th = logf(gh / (rh + 1e-8f));
        float l1v = smooth_l1(d[4] + rb0 - tx) + smooth_l1(d[5] + rb1 - ty)
                  + smooth_l1(d[6] + rb2 - tw) + smooth_l1(d[7] + rb3 - th);
        acc_l1 = l1v * mask * ps;
    }

    // ---- full-wave butterfly sum of the three partials
    #pragma unroll
    for (int off = 32; off > 0; off >>= 1) {
        acc_cnum += __shfl_xor(acc_cnum, off);
        acc_cden += __shfl_xor(acc_cden, off);
        acc_l1   += __shfl_xor(acc_l1,   off);
    }
    if (lane == 0) {
        s_red[w][0] = acc_cnum;
        s_red[w][1] = acc_cden;
        s_red[w][2] = acc_l1;
    }
    __syncthreads();
    if (tid == 0) {
        float a = 0.0f, bb = 0.0f, cc = 0.0f;
        #pragma unroll
        for (int wv = 0; wv < WAVES; ++wv) {
            a  += s_red[wv][0];
            bb += s_red[wv][1];
            cc += s_red[wv][2];
        }
        atomicAdd(&partials[b * 3 + 0], a);
        atomicAdd(&partials[b * 3 + 1], bb);
        atomicAdd(&partials[b * 3 + 2], cc);
    }
}

__global__ void det_final(const float* __restrict__ partials, float* __restrict__ out)
{
    if (threadIdx.x == 0 && blockIdx.x == 0) {
        float cl = 0.0f, l1 = 0.0f;
        #pragma unroll
        for (int b = 0; b < BS; ++b) {
            cl += partials[b * 3 + 0] / (partials[b * 3 + 1] + 1e-7f);
            l1 += partials[b * 3 + 2];
        }
        out[0] = cl / ((float)BS + 1e-7f) + l1 / (float)(BS * P);
    }
}

extern "C" void kernel_launch(void* const* d_in, const int* in_sizes, int n_in,
                              void* d_out, int out_size, void* d_ws, size_t ws_size,
                              hipStream_t stream) {
    const float* v         = (const float*)d_in[0];
    const float* gt        = (const float*)d_in[1];
    const float* rois      = (const float*)d_in[2];
    const float* labels    = (const float*)d_in[3];
    const float* pre_score = (const float*)d_in[4];
    const float* cls_w     = (const float*)d_in[5];
    const float* cls_b     = (const float*)d_in[6];
    const float* reg_w     = (const float*)d_in[7];
    const float* reg_b     = (const float*)d_in[8];
    float* partials = (float*)d_ws;
    float* out      = (float*)d_out;

    hipMemsetAsync(d_ws, 0, BS * 3 * sizeof(float), stream);
    det_main<<<(BS * P) / ROWS_PER_BLOCK, BLOCK, 0, stream>>>(
        v, gt, rois, labels, pre_score, cls_w, cls_b, reg_w, reg_b, partials);
    det_final<<<1, 64, 0, stream>>>(partials, out);
}